// Round 11
// baseline (322.816 us; speedup 1.0000x reference)
//
#include <hip/hip_runtime.h>
#include <stdint.h>

constexpr int K      = 49;           // 7x7 kernel flattened
constexpr int C      = 32;           // out channels
constexpr int TILE   = 64;           // windows per block
constexpr int TILE_F = TILE * K;     // 3136 floats = 12544 B
constexpr int BLK    = 256;          // 4 waves/block, 8 channels each
constexpr int CPW    = C / 4;        // 8

#define GPTR(p) ((const __attribute__((address_space(1))) uint32_t*)(p))
#define LPTR(p) ((__attribute__((address_space(3))) uint32_t*)(p))

// Single-buffer max-occupancy variant: 12.5 KB LDS/block, 4 waves/block ->
// 8 blocks/CU = 32 waves/CU (wave-slot cap, LDS 100 KB). No prefetch loop:
// R10 proved hipcc's alias-conservative ordering defeats src-level
// global_load_lds pipelining; the simple drain + max TLP is the fair test.
__global__ __launch_bounds__(BLK, 8) void conv2d_occ32(
    const float* __restrict__ enc_x,
    const float* __restrict__ weight,   // [C*K]; SGPR base -> s_load_dwordx16
    const float* __restrict__ bias,     // [C]
    float* __restrict__ out,            // [C * windows_nb]
    int windows_nb)
{
    __shared__ __align__(16) float xs[TILE_F];   // 12544 B

    const int t    = threadIdx.x;
    const int lane = t & 63;
    const int widv = t >> 6;                     // divergent form: staging only
    const size_t b = blockIdx.x;
    const float* __restrict__ g = enc_x + b * (size_t)TILE_F;

    // Stage 12544 B, split across the 4 waves: waves 0-2 -> 3 x (64 x 16B),
    // wave 3 -> 3 x 16B rounds + 64 x 4B tail. Coalesced, single burst.
    if (widv < 3) {
#pragma unroll
        for (int r = 0; r < 3; ++r) {
            const int rr = widv * 3 + r;
            __builtin_amdgcn_global_load_lds(GPTR(g + rr * 256 + lane * 4),
                                             LPTR(xs + rr * 256 + lane * 4), 16, 0, 0);
        }
    } else {
#pragma unroll
        for (int rr = 9; rr < 12; ++rr)
            __builtin_amdgcn_global_load_lds(GPTR(g + rr * 256 + lane * 4),
                                             LPTR(xs + rr * 256 + lane * 4), 16, 0, 0);
        __builtin_amdgcn_global_load_lds(GPTR(g + 3072 + lane),
                                         LPTR(xs + 3072 + lane), 4, 0, 0);
    }

    asm volatile("s_waitcnt vmcnt(0)" ::: "memory");
    __builtin_amdgcn_s_barrier();                // whole tile resident

    // Wave-uniform channel base (SGPR) -> weight/bias/out stay SCALAR.
    // (R3/R5/R8 root-cause: t>>6-derived base -> per-lane vector weight loads.)
    const int c0 = __builtin_amdgcn_readfirstlane(widv) * CPW;
    const float* __restrict__ wp = weight + c0 * K;
    float bia[CPW];
#pragma unroll
    for (int cc = 0; cc < CPW; ++cc) bia[cc] = bias[c0 + cc];

    // Lane's window row -> regs. Stride 49 (odd) -> 2 lanes/bank -> free.
    float x[K];
#pragma unroll
    for (int k = 0; k < K; ++k) x[k] = xs[lane * K + k];

    const size_t w = b * (size_t)TILE + lane;

    // 8 channels, c-outer, k fully unrolled: 49 consecutive weights/channel
    // -> wide s_loads; unroll 2 pipelines next channel's s_loads under FMAs.
#pragma unroll 2
    for (int cc = 0; cc < CPW; ++cc) {
        const float* __restrict__ wc = wp + cc * K;
        float a0 = bia[cc], a1 = 0.f, a2 = 0.f, a3 = 0.f;
#pragma unroll
        for (int k = 0; k < K; k += 4) {
            a0 = fmaf(x[k], wc[k], a0);
            if (k + 1 < K) a1 = fmaf(x[k + 1], wc[k + 1], a1);
            if (k + 2 < K) a2 = fmaf(x[k + 2], wc[k + 2], a2);
            if (k + 3 < K) a3 = fmaf(x[k + 3], wc[k + 3], a3);
        }
        // plain store (R10: nontemporal inflated WRITE +25% and FETCH +35%)
        out[(size_t)(c0 + cc) * windows_nb + w] = (a0 + a1) + (a2 + a3);
    }
}

// Known-good fallback (R9, 79.5 us) for unexpected sizes.
__global__ __launch_bounds__(128, 8) void conv2d_split2u(
    const float* __restrict__ enc_x, const float* __restrict__ weight,
    const float* __restrict__ bias, float* __restrict__ out, int windows_nb)
{
    __shared__ __align__(16) float xs[TILE_F];
    const int t = threadIdx.x, lane = t & 63, wid = t >> 6;
    const size_t b = blockIdx.x;
    const float* __restrict__ g = enc_x + b * (size_t)TILE_F;
    if (wid == 0) {
#pragma unroll
        for (int r = 0; r < 6; ++r)
            __builtin_amdgcn_global_load_lds(GPTR(g + r * 256 + lane * 4),
                                             LPTR(xs + r * 256 + lane * 4), 16, 0, 0);
    } else {
#pragma unroll
        for (int r = 6; r < 12; ++r)
            __builtin_amdgcn_global_load_lds(GPTR(g + r * 256 + lane * 4),
                                             LPTR(xs + r * 256 + lane * 4), 16, 0, 0);
        __builtin_amdgcn_global_load_lds(GPTR(g + 3072 + lane),
                                         LPTR(xs + 3072 + lane), 4, 0, 0);
    }
    asm volatile("s_waitcnt vmcnt(0)" ::: "memory");
    __builtin_amdgcn_s_barrier();
    const int c0 = __builtin_amdgcn_readfirstlane(wid) * 16;
    const float* __restrict__ wp = weight + c0 * K;
    float acc[16];
#pragma unroll
    for (int cc = 0; cc < 16; ++cc) acc[cc] = bias[c0 + cc];
    float x[25];
#pragma unroll
    for (int k = 0; k < 24; ++k) x[k] = xs[lane * K + k];
#pragma unroll 2
    for (int cc = 0; cc < 16; ++cc) {
        const float* __restrict__ wc = wp + cc * K;
        float a = acc[cc];
#pragma unroll
        for (int k = 0; k < 24; ++k) a = fmaf(x[k], wc[k], a);
        acc[cc] = a;
    }
#pragma unroll
    for (int k = 0; k < 25; ++k) x[k] = xs[lane * K + 24 + k];
#pragma unroll 2
    for (int cc = 0; cc < 16; ++cc) {
        const float* __restrict__ wc = wp + cc * K + 24;
        float a = acc[cc];
#pragma unroll
        for (int k = 0; k < 25; ++k) a = fmaf(x[k], wc[k], a);
        acc[cc] = a;
    }
    const size_t w = b * TILE + lane;
#pragma unroll
    for (int cc = 0; cc < 16; ++cc)
        out[(size_t)(c0 + cc) * windows_nb + w] = acc[cc];
}

extern "C" void kernel_launch(void* const* d_in, const int* in_sizes, int n_in,
                              void* d_out, int out_size, void* d_ws, size_t ws_size,
                              hipStream_t stream) {
    const float* enc_x  = (const float*)d_in[0];
    const float* weight = (const float*)d_in[1];   // [C,7,7] flat
    const float* bias   = (const float*)d_in[2];   // [C]
    float* out = (float*)d_out;

    const int windows_nb = in_sizes[0] / K;        // 1048576 expected

    if ((windows_nb % TILE) == 0) {
        conv2d_occ32<<<windows_nb / TILE, BLK, 0, stream>>>(enc_x, weight, bias, out, windows_nb);
    } else {
        conv2d_split2u<<<(windows_nb + TILE - 1) / TILE, 128, 0, stream>>>(enc_x, weight, bias, out, windows_nb);
    }
}

// Round 12
// 104.028 us; speedup vs baseline: 3.1032x; 3.1032x over previous
//
#include <hip/hip_runtime.h>
#include <stdint.h>

constexpr int K      = 49;           // 7x7 kernel flattened
constexpr int C      = 32;           // out channels
constexpr int TILE   = 64;           // windows per tile
constexpr int TILE_F = TILE * K;     // 3136 floats = 12544 B
constexpr int BLK    = 128;          // 2 waves/block, 16 channels each
constexpr int NT     = 8;            // tiles per block
constexpr int GRID   = 2048;         // 2048*8*64 = 1048576 windows

#define GPTR(p) ((const __attribute__((address_space(1))) uint32_t*)(p))
#define LPTR(p) ((__attribute__((address_space(3))) uint32_t*)(p))
#define WAITV(n) asm volatile("s_waitcnt vmcnt(" #n ")" ::: "memory")

// Per-wave share of one 12544B tile stage. wave0: rounds 0-5 (6 ops);
// wave1: rounds 6-11 + 256B tail (7 ops). Coalesced 16B/lane.
__device__ __forceinline__ void stage_half(const float* __restrict__ g,
                                           float* slot, int wuni, int lane) {
    if (wuni == 0) {
#pragma unroll
        for (int r = 0; r < 6; ++r)
            __builtin_amdgcn_global_load_lds(GPTR(g + r * 256 + lane * 4),
                                             LPTR(slot + r * 256 + lane * 4), 16, 0, 0);
    } else {
#pragma unroll
        for (int r = 6; r < 12; ++r)
            __builtin_amdgcn_global_load_lds(GPTR(g + r * 256 + lane * 4),
                                             LPTR(slot + r * 256 + lane * 4), 16, 0, 0);
        __builtin_amdgcn_global_load_lds(GPTR(g + 3072 + lane),
                                         LPTR(slot + 3072 + lane), 4, 0, 0);
    }
}

// Ring-2, statically-named buffers, fully unrolled tile loop.
// Per-wave VMEM FIFO (L = own stage ops: 6 or 7; S = 16 stores):
//   issue: P0 P1 | [w0] c0 S0 b2 P2 | [w1] c1 S1 b2 P3 | ...
//   wait_j (tile j resident): younger = S_{j-1}(16) + P_{j+1}(L)
//     j=0: L ; 1<=j<=NT-2: 16+L ; j=NT-1: 16.
// Stores/next-stage are always YOUNGER than the waited load -> never chain.
__global__ __launch_bounds__(BLK, 3) void conv2d_ring2s(
    const float* __restrict__ enc_x,
    const float* __restrict__ weight,   // [C*K]; SGPR base -> s_load_dwordx16
    const float* __restrict__ bias,     // [C]
    float* __restrict__ out,            // [C * windows_nb]
    int windows_nb)
{
    __shared__ __align__(16) float bufA[TILE_F];   // static names: alias-disjoint
    __shared__ __align__(16) float bufB[TILE_F];   // (R10 bug: runtime-selected ptr)

    const int t    = threadIdx.x;
    const int lane = t & 63;
    const int wuni = __builtin_amdgcn_readfirstlane(t >> 6);  // SGPR wave id
    const size_t b = blockIdx.x;
    const float* __restrict__ gbase = enc_x + b * (size_t)(NT * TILE_F);

    // Prologue: T0 -> A, T1 -> B.
    stage_half(gbase + 0 * TILE_F, bufA, wuni, lane);
    stage_half(gbase + 1 * TILE_F, bufB, wuni, lane);

    const int c0 = wuni * 16;
    const float* __restrict__ wp = weight + c0 * K;
    float bia[16];
#pragma unroll
    for (int cc = 0; cc < 16; ++cc) bia[cc] = bias[c0 + cc];

#pragma unroll
    for (int j = 0; j < NT; ++j) {
        // --- counted wait for tile j (own share), then block-wide barrier ---
        if (j == 0)          { if (wuni == 0) WAITV(6);  else WAITV(7);  }
        else if (j < NT - 1) { if (wuni == 0) WAITV(22); else WAITV(23); }
        else                 { WAITV(16); }
        __builtin_amdgcn_s_barrier();        // both waves waited -> tile j resident

        const float* __restrict__ xs = (j & 1) ? bufB : bufA;   // j const (unrolled)
        float* __restrict__ dst      = (j & 1) ? bufB : bufA;   // stage target = same slot

        float acc[16];
#pragma unroll
        for (int cc = 0; cc < 16; ++cc) acc[cc] = bia[cc];

        // k half 1: 0..23  (stride 49: odd -> 2 lanes/bank, conflict-free)
        float x[25];
#pragma unroll
        for (int k = 0; k < 24; ++k) x[k] = xs[lane * K + k];
#pragma unroll 2
        for (int cc = 0; cc < 16; ++cc) {
            const float* __restrict__ wc = wp + cc * K;
            float a = acc[cc];
#pragma unroll
            for (int k = 0; k < 24; ++k) a = fmaf(x[k], wc[k], a);
            acc[cc] = a;
        }
        // k half 2: 24..48
#pragma unroll
        for (int k = 0; k < 25; ++k) x[k] = xs[lane * K + 24 + k];
#pragma unroll 2
        for (int cc = 0; cc < 16; ++cc) {
            const float* __restrict__ wc = wp + cc * K + 24;
            float a = acc[cc];
#pragma unroll
            for (int k = 0; k < 25; ++k) a = fmaf(x[k], wc[k], a);
            acc[cc] = a;
        }

        const size_t w = (b * NT + j) * (size_t)TILE + lane;
#pragma unroll
        for (int cc = 0; cc < 16; ++cc)     // 16 x 256B contiguous plain stores
            out[(size_t)(c0 + cc) * windows_nb + w] = acc[cc];

        // --- refill this buffer with tile j+2 (both waves done reading it) ---
        if (j + 2 < NT) {
            asm volatile("" ::: "memory");
            __builtin_amdgcn_s_barrier();    // partner's ds_reads of slot complete
            stage_half(gbase + (size_t)(j + 2) * TILE_F, dst, wuni, lane);
        }
    }
}

// Known-good fallback (R9, 79.5 us) for unexpected sizes.
__global__ __launch_bounds__(128, 8) void conv2d_split2u(
    const float* __restrict__ enc_x, const float* __restrict__ weight,
    const float* __restrict__ bias, float* __restrict__ out, int windows_nb)
{
    __shared__ __align__(16) float xs[TILE_F];
    const int t = threadIdx.x, lane = t & 63, wid = t >> 6;
    const size_t b = blockIdx.x;
    const float* __restrict__ g = enc_x + b * (size_t)TILE_F;
    if (wid == 0) {
#pragma unroll
        for (int r = 0; r < 6; ++r)
            __builtin_amdgcn_global_load_lds(GPTR(g + r * 256 + lane * 4),
                                             LPTR(xs + r * 256 + lane * 4), 16, 0, 0);
    } else {
#pragma unroll
        for (int r = 6; r < 12; ++r)
            __builtin_amdgcn_global_load_lds(GPTR(g + r * 256 + lane * 4),
                                             LPTR(xs + r * 256 + lane * 4), 16, 0, 0);
        __builtin_amdgcn_global_load_lds(GPTR(g + 3072 + lane),
                                         LPTR(xs + 3072 + lane), 4, 0, 0);
    }
    asm volatile("s_waitcnt vmcnt(0)" ::: "memory");
    __builtin_amdgcn_s_barrier();
    const int c0 = __builtin_amdgcn_readfirstlane(wid) * 16;
    const float* __restrict__ wp = weight + c0 * K;
    float acc[16];
#pragma unroll
    for (int cc = 0; cc < 16; ++cc) acc[cc] = bias[c0 + cc];
    float x[25];
#pragma unroll
    for (int k = 0; k < 24; ++k) x[k] = xs[lane * K + k];
#pragma unroll 2
    for (int cc = 0; cc < 16; ++cc) {
        const float* __restrict__ wc = wp + cc * K;
        float a = acc[cc];
#pragma unroll
        for (int k = 0; k < 24; ++k) a = fmaf(x[k], wc[k], a);
        acc[cc] = a;
    }
#pragma unroll
    for (int k = 0; k < 25; ++k) x[k] = xs[lane * K + 24 + k];
#pragma unroll 2
    for (int cc = 0; cc < 16; ++cc) {
        const float* __restrict__ wc = wp + cc * K + 24;
        float a = acc[cc];
#pragma unroll
        for (int k = 0; k < 25; ++k) a = fmaf(x[k], wc[k], a);
        acc[cc] = a;
    }
    const size_t w = b * TILE + lane;
#pragma unroll
    for (int cc = 0; cc < 16; ++cc)
        out[(size_t)(c0 + cc) * windows_nb + w] = acc[cc];
}

extern "C" void kernel_launch(void* const* d_in, const int* in_sizes, int n_in,
                              void* d_out, int out_size, void* d_ws, size_t ws_size,
                              hipStream_t stream) {
    const float* enc_x  = (const float*)d_in[0];
    const float* weight = (const float*)d_in[1];   // [C,7,7] flat
    const float* bias   = (const float*)d_in[2];   // [C]
    float* out = (float*)d_out;

    const int windows_nb = in_sizes[0] / K;        // 1048576 expected

    if (windows_nb == GRID * NT * TILE) {
        conv2d_ring2s<<<GRID, BLK, 0, stream>>>(enc_x, weight, bias, out, windows_nb);
    } else {
        conv2d_split2u<<<(windows_nb + TILE - 1) / TILE, 128, 0, stream>>>(enc_x, weight, bias, out, windows_nb);
    }
}